// Round 1
// baseline (322.621 us; speedup 1.0000x reference)
//
#include <hip/hip_runtime.h>
#include <hip/hip_bf16.h>

// Problem constants (B=2, T=2048, H=4, D=2048)
#define FD 8192      // H*D flat dim
#define DD 2048      // D
#define NH 4         // heads
#define NT 4096      // B*T tokens
#define NG 24        // gate rows: 4 pre + 16 res + 4 post
#define KSPLIT 16
#define KC (FD / KSPLIT)   // 512 k per gates-block
#define CHUNK 32

typedef __attribute__((ext_vector_type(4))) float f32x4;
typedef __attribute__((ext_vector_type(8))) short short8;

__device__ inline unsigned short f2bf(float f) {
  __hip_bfloat16 h = __float2bfloat16(f);
  unsigned short u; __builtin_memcpy(&u, &h, 2); return u;
}
__device__ inline float bf2f(unsigned short u) {
  __hip_bfloat16 h; __builtin_memcpy(&h, &u, 2); return __bfloat162float(h);
}

// ---------------------------------------------------------------- prep
// Convert w_inner -> bf16; build wn[j][k] = gateW[j][k] * norm_w[k]
__global__ __launch_bounds__(256) void k_prep(
    const float* __restrict__ w_inner,
    const float* __restrict__ w_pre,
    const float* __restrict__ w_res,
    const float* __restrict__ w_post,
    const float* __restrict__ norm_w,
    unsigned short* __restrict__ w_inner_bf,
    float* __restrict__ wn)
{
  int stride = gridDim.x * blockDim.x;
  int gid = blockIdx.x * blockDim.x + threadIdx.x;
  for (int i = gid; i < DD * DD; i += stride) w_inner_bf[i] = f2bf(w_inner[i]);
  for (int i = gid; i < NG * FD; i += stride) {
    int j = i >> 13, k = i & (FD - 1);
    float w = (j < 4) ? w_pre[j * FD + k]
            : (j < 20) ? w_res[(j - 4) * FD + k]
            : w_post[(j - 20) * FD + k];
    wn[i] = w * norm_w[k];
  }
}

// ---------------------------------------------------------------- gates GEMM + sumsq
// Block: 256 tokens x 512 K-slice. Deterministic per-split partials.
__global__ __launch_bounds__(256) void k_gates(
    const float* __restrict__ x, const float* __restrict__ wn,
    float* __restrict__ partial /* [KSPLIT][NT][NG+1] */)
{
  __shared__ float xs[256][CHUNK + 1];
  const int tt = blockIdx.x;   // token tile 0..15
  const int ks = blockIdx.y;   // k split   0..15
  const int tid = threadIdx.x;
  const int t0 = tt * 256;
  const int k0 = ks * KC;
  float part[NG];
#pragma unroll
  for (int j = 0; j < NG; ++j) part[j] = 0.f;
  float ssq = 0.f;

  for (int ch = 0; ch < KC; ch += CHUNK) {
    __syncthreads();
#pragma unroll
    for (int it = 0; it < 8; ++it) {
      int f = it * 256 + tid;
      int r = f >> 3, cf = f & 7;
      f32x4 v = *(const f32x4*)&x[(size_t)(t0 + r) * FD + k0 + ch + cf * 4];
      xs[r][cf * 4 + 0] = v.x; xs[r][cf * 4 + 1] = v.y;
      xs[r][cf * 4 + 2] = v.z; xs[r][cf * 4 + 3] = v.w;
    }
    __syncthreads();
#pragma unroll 4
    for (int c = 0; c < CHUNK; ++c) {
      float xv = xs[tid][c];
      ssq += xv * xv;
      int kk = k0 + ch + c;
#pragma unroll
      for (int j = 0; j < NG; ++j) part[j] += xv * wn[j * FD + kk];
    }
  }
  float* dst = &partial[((size_t)ks * NT + (t0 + tid)) * (NG + 1)];
#pragma unroll
  for (int j = 0; j < NG; ++j) dst[j] = part[j];
  dst[NG] = ssq;
}

// ---------------------------------------------------------------- per-token scalars
__global__ __launch_bounds__(256) void k_scalars(
    const float* __restrict__ partial,
    const float* __restrict__ alpha_pre, const float* __restrict__ alpha_res,
    const float* __restrict__ alpha_post,
    const float* __restrict__ s_pre, const float* __restrict__ s_res,
    const float* __restrict__ s_post,
    float* __restrict__ gates /* [NT][24]: a0..3, c0..3, b0..15 */)
{
  int t = blockIdx.x * blockDim.x + threadIdx.x;
  if (t >= NT) return;
  float acc[NG + 1];
#pragma unroll
  for (int j = 0; j <= NG; ++j) acc[j] = 0.f;
  for (int s = 0; s < KSPLIT; ++s) {
    const float* p = &partial[((size_t)s * NT + t) * (NG + 1)];
#pragma unroll
    for (int j = 0; j <= NG; ++j) acc[j] += p[j];
  }
  float rinv = rsqrtf(acc[NG] * (1.0f / FD) + 1e-6f);
  float ap = alpha_pre[0], ar = alpha_res[0], apo = alpha_post[0];

  float out[NG];
#pragma unroll
  for (int h = 0; h < 4; ++h)
    out[h] = 1.f / (1.f + expf(-(ap * rinv * acc[h] + s_pre[h])));
#pragma unroll
  for (int h = 0; h < 4; ++h)
    out[4 + h] = 2.f / (1.f + expf(-(apo * rinv * acc[20 + h] + s_post[h])));

  // Sinkhorn on 4x4
  float m[16]; float mx = -1e30f;
#pragma unroll
  for (int j = 0; j < 16; ++j) {
    float br = ar * rinv * acc[4 + j] + s_res[j];
    m[j] = br; mx = fmaxf(mx, br);
  }
#pragma unroll
  for (int j = 0; j < 16; ++j) m[j] = expf(m[j] - mx);
#pragma unroll
  for (int it = 0; it < 5; ++it) {
#pragma unroll
    for (int h = 0; h < 4; ++h) {
      float rs = m[h*4] + m[h*4+1] + m[h*4+2] + m[h*4+3];
      float inv = 1.f / (rs + 1e-12f);
      m[h*4] *= inv; m[h*4+1] *= inv; m[h*4+2] *= inv; m[h*4+3] *= inv;
    }
#pragma unroll
    for (int k = 0; k < 4; ++k) {
      float cs = m[k] + m[4+k] + m[8+k] + m[12+k];
      float inv = 1.f / (cs + 1e-12f);
      m[k] *= inv; m[4+k] *= inv; m[8+k] *= inv; m[12+k] *= inv;
    }
  }
#pragma unroll
  for (int j = 0; j < 16; ++j) out[8 + j] = m[j];

  float* gt = &gates[(size_t)t * 24];
#pragma unroll
  for (int j = 0; j < NG; ++j) gt[j] = out[j];
}

// ---------------------------------------------------------------- inner_in = sum_h a_h * x_h  (bf16 out)
__global__ __launch_bounds__(256) void k_inner_in(
    const float* __restrict__ x, const float* __restrict__ gates,
    unsigned short* __restrict__ inner_in)
{
  int t = blockIdx.x, tid = threadIdx.x;
  const float* g = &gates[(size_t)t * 24];
  float a0 = g[0], a1 = g[1], a2 = g[2], a3 = g[3];
  const float* xt = &x[(size_t)t * FD];
#pragma unroll
  for (int it = 0; it < 2; ++it) {
    int d = (it * 256 + tid) * 4;
    f32x4 v0 = *(const f32x4*)&xt[0 * DD + d];
    f32x4 v1 = *(const f32x4*)&xt[1 * DD + d];
    f32x4 v2 = *(const f32x4*)&xt[2 * DD + d];
    f32x4 v3 = *(const f32x4*)&xt[3 * DD + d];
    f32x4 s = a0 * v0 + a1 * v1 + a2 * v2 + a3 * v3;
    ushort4 o;
    o.x = f2bf(s.x); o.y = f2bf(s.y); o.z = f2bf(s.z); o.w = f2bf(s.w);
    *(ushort4*)&inner_in[(size_t)t * DD + d] = o;
  }
}

// ---------------------------------------------------------------- GEMM: inner_out = inner_in @ w_inner^T  (bf16 MFMA)
// M=4096 (tokens), N=2048 (d), K=2048. Both operands row-major with contiguous K.
__global__ __launch_bounds__(256) void k_gemm(
    const unsigned short* __restrict__ A,   // inner_in [NT][2048]
    const unsigned short* __restrict__ B,   // w_inner_bf [2048][2048]
    unsigned short* __restrict__ C)         // inner_out [NT][2048]
{
  int bid = blockIdx.x;
  int bm = bid >> 4, bn = bid & 15;         // 32 x 16 tiles of 128x128
  int tid = threadIdx.x;
  int wave = tid >> 6, lane = tid & 63;
  int wm = wave >> 1, wn_ = wave & 1;       // 2x2 waves of 64x64
  int lr = lane & 15, kg = lane >> 4;
  int row_base = bm * 128 + wm * 64;
  int col_base = bn * 128 + wn_ * 64;
  f32x4 acc[4][4] = {};

  for (int k0 = 0; k0 < 2048; k0 += 32) {
    short8 a[4], b[4];
#pragma unroll
    for (int m = 0; m < 4; ++m)
      a[m] = *(const short8*)&A[(size_t)(row_base + m * 16 + lr) * 2048 + k0 + kg * 8];
#pragma unroll
    for (int n = 0; n < 4; ++n)
      b[n] = *(const short8*)&B[(size_t)(col_base + n * 16 + lr) * 2048 + k0 + kg * 8];
#pragma unroll
    for (int m = 0; m < 4; ++m)
#pragma unroll
      for (int n = 0; n < 4; ++n)
        acc[m][n] = __builtin_amdgcn_mfma_f32_16x16x32_bf16(a[m], b[n], acc[m][n], 0, 0, 0);
  }
  // D layout (verified): col = lane&15, row = (lane>>4)*4 + reg
#pragma unroll
  for (int m = 0; m < 4; ++m)
#pragma unroll
    for (int n = 0; n < 4; ++n) {
      int col = col_base + n * 16 + lr;
#pragma unroll
      for (int r = 0; r < 4; ++r) {
        int row = row_base + m * 16 + kg * 4 + r;
        C[(size_t)row * 2048 + col] = f2bf(acc[m][n][r]);
      }
    }
}

// ---------------------------------------------------------------- out = carry + write
__global__ __launch_bounds__(256) void k_out(
    const float* __restrict__ x, const float* __restrict__ gates,
    const unsigned short* __restrict__ inner_out, float* __restrict__ out)
{
  int t = blockIdx.x, tid = threadIdx.x;
  const float* g = &gates[(size_t)t * 24];
  float c[4], bl[16];
#pragma unroll
  for (int h = 0; h < 4; ++h) c[h] = g[4 + h];
#pragma unroll
  for (int j = 0; j < 16; ++j) bl[j] = g[8 + j];
  const float* xt = &x[(size_t)t * FD];
  float* ot = &out[(size_t)t * FD];
  const unsigned short* iot = &inner_out[(size_t)t * DD];
#pragma unroll
  for (int it = 0; it < 2; ++it) {
    int d = (it * 256 + tid) * 4;
    f32x4 xk[4];
#pragma unroll
    for (int k = 0; k < 4; ++k) xk[k] = *(const f32x4*)&xt[k * DD + d];
    ushort4 u = *(const ushort4*)&iot[d];
    f32x4 io; io.x = bf2f(u.x); io.y = bf2f(u.y); io.z = bf2f(u.z); io.w = bf2f(u.w);
#pragma unroll
    for (int h = 0; h < 4; ++h) {
      f32x4 o = c[h] * io
              + bl[h*4+0] * xk[0] + bl[h*4+1] * xk[1]
              + bl[h*4+2] * xk[2] + bl[h*4+3] * xk[3];
      *(f32x4*)&ot[h * DD + d] = o;
    }
  }
}

// ---------------------------------------------------------------- launch
extern "C" void kernel_launch(void* const* d_in, const int* in_sizes, int n_in,
                              void* d_out, int out_size, void* d_ws, size_t ws_size,
                              hipStream_t stream) {
  const float* x          = (const float*)d_in[0];
  const float* norm_w     = (const float*)d_in[1];
  const float* w_pre      = (const float*)d_in[2];
  const float* w_res      = (const float*)d_in[3];
  const float* w_post     = (const float*)d_in[4];
  const float* alpha_pre  = (const float*)d_in[5];
  const float* alpha_res  = (const float*)d_in[6];
  const float* alpha_post = (const float*)d_in[7];
  const float* s_pre      = (const float*)d_in[8];
  const float* s_res      = (const float*)d_in[9];
  const float* s_post     = (const float*)d_in[10];
  const float* w_inner    = (const float*)d_in[11];
  float* out = (float*)d_out;

  char* ws = (char*)d_ws;
  size_t off = 0;
  auto alloc = [&](size_t bytes) -> void* {
    void* p = ws + off;
    off = (off + bytes + 255) & ~(size_t)255;
    return p;
  };
  unsigned short* w_inner_bf = (unsigned short*)alloc((size_t)DD * DD * 2);   // 8.4 MB
  unsigned short* inner_in   = (unsigned short*)alloc((size_t)NT * DD * 2);   // 16.8 MB
  unsigned short* inner_out  = (unsigned short*)alloc((size_t)NT * DD * 2);   // 16.8 MB
  float* wn      = (float*)alloc((size_t)NG * FD * 4);                        // 0.79 MB
  float* partial = (float*)alloc((size_t)KSPLIT * NT * (NG + 1) * 4);         // 6.55 MB
  float* gates   = (float*)alloc((size_t)NT * 24 * 4);                        // 0.39 MB

  k_prep<<<1024, 256, 0, stream>>>(w_inner, w_pre, w_res, w_post, norm_w, w_inner_bf, wn);
  k_gates<<<dim3(16, 16), 256, 0, stream>>>(x, wn, partial);
  k_scalars<<<16, 256, 0, stream>>>(partial, alpha_pre, alpha_res, alpha_post,
                                    s_pre, s_res, s_post, gates);
  k_inner_in<<<4096, 256, 0, stream>>>(x, gates, inner_in);
  k_gemm<<<512, 256, 0, stream>>>(inner_in, w_inner_bf, inner_out);
  k_out<<<4096, 256, 0, stream>>>(x, gates, inner_out, out);
}

// Round 2
// 243.718 us; speedup vs baseline: 1.3237x; 1.3237x over previous
//
#include <hip/hip_runtime.h>
#include <hip/hip_bf16.h>

// Problem constants (B=2, T=2048, H=4, D=2048)
#define FD 8192      // H*D flat dim
#define DD 2048      // D
#define NH 4         // heads
#define NT 4096      // B*T tokens
#define NG 24        // gate rows: 4 pre + 16 res + 4 post
#define NGP 32       // padded gate rows for MFMA
#define KSPLIT 32
#define KC (FD / KSPLIT)   // 256 k per gates-block
#define CH 64              // k per staging chunk

typedef __attribute__((ext_vector_type(4))) float f32x4;
typedef __attribute__((ext_vector_type(8))) short short8;

__device__ inline unsigned short f2bf(float f) {
  __hip_bfloat16 h = __float2bfloat16(f);
  unsigned short u; __builtin_memcpy(&u, &h, 2); return u;
}
__device__ inline float bf2f(unsigned short u) {
  __hip_bfloat16 h; __builtin_memcpy(&h, &u, 2); return __bfloat162float(h);
}

// ---------------------------------------------------------------- prep
// w_inner -> bf16; wnb[j][k] = gateW[j][k] * norm_w[k] in bf16, rows 24..31 = 0
__global__ __launch_bounds__(256) void k_prep(
    const float* __restrict__ w_inner,
    const float* __restrict__ w_pre,
    const float* __restrict__ w_res,
    const float* __restrict__ w_post,
    const float* __restrict__ norm_w,
    unsigned short* __restrict__ w_inner_bf,
    unsigned short* __restrict__ wnb)
{
  int stride = gridDim.x * blockDim.x;
  int gid = blockIdx.x * blockDim.x + threadIdx.x;
  for (int i = gid; i < DD * DD; i += stride) w_inner_bf[i] = f2bf(w_inner[i]);
  for (int i = gid; i < NGP * FD; i += stride) {
    int j = i >> 13, k = i & (FD - 1);
    float w = (j < 4) ? w_pre[j * FD + k]
            : (j < 20) ? w_res[(j - 4) * FD + k]
            : (j < 24) ? w_post[(j - 20) * FD + k]
            : 0.0f;
    wnb[i] = f2bf(w * norm_w[k]);
  }
}

// ---------------------------------------------------------------- gates GEMM + sumsq (MFMA)
// Block: 128 tokens x 256 K-slice. 4 waves, each 32 tokens x 32 gates.
__global__ __launch_bounds__(256) void k_gates(
    const float* __restrict__ x, const unsigned short* __restrict__ wnb,
    float* __restrict__ partial /* [KSPLIT][NT][NG+1] */)
{
  __shared__ unsigned short xs[128][72];   // 64 bf16 cols + 8 pad (16B-aligned rows)
  const int tb = blockIdx.x;   // token tile 0..31
  const int ks = blockIdx.y;   // k split   0..31
  const int tid = threadIdx.x;
  const int wave = tid >> 6, lane = tid & 63;
  const int lr = lane & 15, kg = lane >> 4;
  const int t0 = tb * 128;
  const int k0 = ks * KC;
  const int sr = tid >> 4;           // staging sub-row 0..15
  const int sc = (tid & 15) * 4;     // staging col 0..60

  float ssq[8];
#pragma unroll
  for (int i = 0; i < 8; ++i) ssq[i] = 0.f;
  f32x4 acc[2][2] = {};

  for (int ch = 0; ch < KC; ch += CH) {
    __syncthreads();
#pragma unroll
    for (int it = 0; it < 8; ++it) {
      int r = it * 16 + sr;
      f32x4 v = *(const f32x4*)&x[(size_t)(t0 + r) * FD + k0 + ch + sc];
      ssq[it] += v.x * v.x + v.y * v.y + v.z * v.z + v.w * v.w;
      ushort4 o;
      o.x = f2bf(v.x); o.y = f2bf(v.y); o.z = f2bf(v.z); o.w = f2bf(v.w);
      *(ushort4*)&xs[r][sc] = o;
    }
    __syncthreads();
#pragma unroll
    for (int kk = 0; kk < CH; kk += 32) {
      short8 a[2], b[2];
#pragma unroll
      for (int m = 0; m < 2; ++m)
        a[m] = *(const short8*)&xs[wave * 32 + m * 16 + lr][kk + kg * 8];
#pragma unroll
      for (int n = 0; n < 2; ++n)
        b[n] = *(const short8*)&wnb[(size_t)(n * 16 + lr) * FD + k0 + ch + kk + kg * 8];
#pragma unroll
      for (int m = 0; m < 2; ++m)
#pragma unroll
        for (int n = 0; n < 2; ++n)
          acc[m][n] = __builtin_amdgcn_mfma_f32_16x16x32_bf16(a[m], b[n], acc[m][n], 0, 0, 0);
    }
  }

  // gate partials: D layout col=lane&15 -> gate, row=(lane>>4)*4+reg -> token
  float* base = &partial[(size_t)ks * NT * (NG + 1)];
#pragma unroll
  for (int m = 0; m < 2; ++m)
#pragma unroll
    for (int n = 0; n < 2; ++n) {
      int g = n * 16 + lr;
      if (g < NG) {
#pragma unroll
        for (int r = 0; r < 4; ++r) {
          int row = wave * 32 + m * 16 + kg * 4 + r;
          base[(size_t)(t0 + row) * (NG + 1) + g] = acc[m][n][r];
        }
      }
    }
  // ssq: reduce across the 16 threads (same tid>>4) covering each row
#pragma unroll
  for (int it = 0; it < 8; ++it) {
    float v = ssq[it];
    v += __shfl_xor(v, 1);
    v += __shfl_xor(v, 2);
    v += __shfl_xor(v, 4);
    v += __shfl_xor(v, 8);
    if ((tid & 15) == 0) {
      int row = it * 16 + sr;
      base[(size_t)(t0 + row) * (NG + 1) + NG] = v;
    }
  }
}

// ---------------------------------------------------------------- per-token scalars
__global__ __launch_bounds__(256) void k_scalars(
    const float* __restrict__ partial,
    const float* __restrict__ alpha_pre, const float* __restrict__ alpha_res,
    const float* __restrict__ alpha_post,
    const float* __restrict__ s_pre, const float* __restrict__ s_res,
    const float* __restrict__ s_post,
    float* __restrict__ gates /* [NT][24]: a0..3, c0..3, b0..15 */)
{
  int t = blockIdx.x * blockDim.x + threadIdx.x;
  if (t >= NT) return;
  float acc[NG + 1];
#pragma unroll
  for (int j = 0; j <= NG; ++j) acc[j] = 0.f;
  for (int s = 0; s < KSPLIT; ++s) {
    const float* p = &partial[((size_t)s * NT + t) * (NG + 1)];
#pragma unroll
    for (int j = 0; j <= NG; ++j) acc[j] += p[j];
  }
  float rinv = rsqrtf(acc[NG] * (1.0f / FD) + 1e-6f);
  float ap = alpha_pre[0], ar = alpha_res[0], apo = alpha_post[0];

  float out[NG];
#pragma unroll
  for (int h = 0; h < 4; ++h)
    out[h] = 1.f / (1.f + expf(-(ap * rinv * acc[h] + s_pre[h])));
#pragma unroll
  for (int h = 0; h < 4; ++h)
    out[4 + h] = 2.f / (1.f + expf(-(apo * rinv * acc[20 + h] + s_post[h])));

  // Sinkhorn on 4x4
  float m[16]; float mx = -1e30f;
#pragma unroll
  for (int j = 0; j < 16; ++j) {
    float br = ar * rinv * acc[4 + j] + s_res[j];
    m[j] = br; mx = fmaxf(mx, br);
  }
#pragma unroll
  for (int j = 0; j < 16; ++j) m[j] = expf(m[j] - mx);
#pragma unroll
  for (int it = 0; it < 5; ++it) {
#pragma unroll
    for (int h = 0; h < 4; ++h) {
      float rs = m[h*4] + m[h*4+1] + m[h*4+2] + m[h*4+3];
      float inv = 1.f / (rs + 1e-12f);
      m[h*4] *= inv; m[h*4+1] *= inv; m[h*4+2] *= inv; m[h*4+3] *= inv;
    }
#pragma unroll
    for (int k = 0; k < 4; ++k) {
      float cs = m[k] + m[4+k] + m[8+k] + m[12+k];
      float inv = 1.f / (cs + 1e-12f);
      m[k] *= inv; m[4+k] *= inv; m[8+k] *= inv; m[12+k] *= inv;
    }
  }
#pragma unroll
  for (int j = 0; j < 16; ++j) out[8 + j] = m[j];

  float* gt = &gates[(size_t)t * 24];
#pragma unroll
  for (int j = 0; j < NG; ++j) gt[j] = out[j];
}

// ---------------------------------------------------------------- inner_in = sum_h a_h * x_h  (bf16 out)
__global__ __launch_bounds__(256) void k_inner_in(
    const float* __restrict__ x, const float* __restrict__ gates,
    unsigned short* __restrict__ inner_in)
{
  int t = blockIdx.x, tid = threadIdx.x;
  const float* g = &gates[(size_t)t * 24];
  float a0 = g[0], a1 = g[1], a2 = g[2], a3 = g[3];
  const float* xt = &x[(size_t)t * FD];
#pragma unroll
  for (int it = 0; it < 2; ++it) {
    int d = (it * 256 + tid) * 4;
    f32x4 v0 = *(const f32x4*)&xt[0 * DD + d];
    f32x4 v1 = *(const f32x4*)&xt[1 * DD + d];
    f32x4 v2 = *(const f32x4*)&xt[2 * DD + d];
    f32x4 v3 = *(const f32x4*)&xt[3 * DD + d];
    f32x4 s = a0 * v0 + a1 * v1 + a2 * v2 + a3 * v3;
    ushort4 o;
    o.x = f2bf(s.x); o.y = f2bf(s.y); o.z = f2bf(s.z); o.w = f2bf(s.w);
    *(ushort4*)&inner_in[(size_t)t * DD + d] = o;
  }
}

// ---------------------------------------------------------------- GEMM: inner_out = inner_in @ w_inner^T  (bf16 MFMA)
__global__ __launch_bounds__(256) void k_gemm(
    const unsigned short* __restrict__ A,   // inner_in [NT][2048]
    const unsigned short* __restrict__ B,   // w_inner_bf [2048][2048]
    unsigned short* __restrict__ C)         // inner_out [NT][2048]
{
  int bid = blockIdx.x;
  int bm = bid >> 4, bn = bid & 15;         // 32 x 16 tiles of 128x128
  int tid = threadIdx.x;
  int wave = tid >> 6, lane = tid & 63;
  int wm = wave >> 1, wn_ = wave & 1;       // 2x2 waves of 64x64
  int lr = lane & 15, kg = lane >> 4;
  int row_base = bm * 128 + wm * 64;
  int col_base = bn * 128 + wn_ * 64;
  f32x4 acc[4][4] = {};

  for (int k0 = 0; k0 < 2048; k0 += 32) {
    short8 a[4], b[4];
#pragma unroll
    for (int m = 0; m < 4; ++m)
      a[m] = *(const short8*)&A[(size_t)(row_base + m * 16 + lr) * 2048 + k0 + kg * 8];
#pragma unroll
    for (int n = 0; n < 4; ++n)
      b[n] = *(const short8*)&B[(size_t)(col_base + n * 16 + lr) * 2048 + k0 + kg * 8];
#pragma unroll
    for (int m = 0; m < 4; ++m)
#pragma unroll
      for (int n = 0; n < 4; ++n)
        acc[m][n] = __builtin_amdgcn_mfma_f32_16x16x32_bf16(a[m], b[n], acc[m][n], 0, 0, 0);
  }
#pragma unroll
  for (int m = 0; m < 4; ++m)
#pragma unroll
    for (int n = 0; n < 4; ++n) {
      int col = col_base + n * 16 + lr;
#pragma unroll
      for (int r = 0; r < 4; ++r) {
        int row = row_base + m * 16 + kg * 4 + r;
        C[(size_t)row * 2048 + col] = f2bf(acc[m][n][r]);
      }
    }
}

// ---------------------------------------------------------------- out = carry + write
__global__ __launch_bounds__(256) void k_out(
    const float* __restrict__ x, const float* __restrict__ gates,
    const unsigned short* __restrict__ inner_out, float* __restrict__ out)
{
  int t = blockIdx.x, tid = threadIdx.x;
  const float* g = &gates[(size_t)t * 24];
  float c[4], bl[16];
#pragma unroll
  for (int h = 0; h < 4; ++h) c[h] = g[4 + h];
#pragma unroll
  for (int j = 0; j < 16; ++j) bl[j] = g[8 + j];
  const float* xt = &x[(size_t)t * FD];
  float* ot = &out[(size_t)t * FD];
  const unsigned short* iot = &inner_out[(size_t)t * DD];
#pragma unroll
  for (int it = 0; it < 2; ++it) {
    int d = (it * 256 + tid) * 4;
    f32x4 xk[4];
#pragma unroll
    for (int k = 0; k < 4; ++k) xk[k] = *(const f32x4*)&xt[k * DD + d];
    ushort4 u = *(const ushort4*)&iot[d];
    f32x4 io; io.x = bf2f(u.x); io.y = bf2f(u.y); io.z = bf2f(u.z); io.w = bf2f(u.w);
#pragma unroll
    for (int h = 0; h < 4; ++h) {
      f32x4 o = c[h] * io
              + bl[h*4+0] * xk[0] + bl[h*4+1] * xk[1]
              + bl[h*4+2] * xk[2] + bl[h*4+3] * xk[3];
      *(f32x4*)&ot[h * DD + d] = o;
    }
  }
}

// ---------------------------------------------------------------- launch
extern "C" void kernel_launch(void* const* d_in, const int* in_sizes, int n_in,
                              void* d_out, int out_size, void* d_ws, size_t ws_size,
                              hipStream_t stream) {
  const float* x          = (const float*)d_in[0];
  const float* norm_w     = (const float*)d_in[1];
  const float* w_pre      = (const float*)d_in[2];
  const float* w_res      = (const float*)d_in[3];
  const float* w_post     = (const float*)d_in[4];
  const float* alpha_pre  = (const float*)d_in[5];
  const float* alpha_res  = (const float*)d_in[6];
  const float* alpha_post = (const float*)d_in[7];
  const float* s_pre      = (const float*)d_in[8];
  const float* s_res      = (const float*)d_in[9];
  const float* s_post     = (const float*)d_in[10];
  const float* w_inner    = (const float*)d_in[11];
  float* out = (float*)d_out;

  char* ws = (char*)d_ws;
  size_t off = 0;
  auto alloc = [&](size_t bytes) -> void* {
    void* p = ws + off;
    off = (off + bytes + 255) & ~(size_t)255;
    return p;
  };
  unsigned short* w_inner_bf = (unsigned short*)alloc((size_t)DD * DD * 2);        // 8.4 MB
  unsigned short* inner_in   = (unsigned short*)alloc((size_t)NT * DD * 2);        // 16.8 MB
  unsigned short* inner_out  = (unsigned short*)alloc((size_t)NT * DD * 2);        // 16.8 MB
  unsigned short* wnb        = (unsigned short*)alloc((size_t)NGP * FD * 2);       // 0.52 MB
  float* partial = (float*)alloc((size_t)KSPLIT * NT * (NG + 1) * 4);              // 13.1 MB
  float* gates   = (float*)alloc((size_t)NT * 24 * 4);                             // 0.39 MB

  k_prep<<<1024, 256, 0, stream>>>(w_inner, w_pre, w_res, w_post, norm_w, w_inner_bf, wnb);
  k_gates<<<dim3(32, 32), 256, 0, stream>>>(x, wnb, partial);
  k_scalars<<<16, 256, 0, stream>>>(partial, alpha_pre, alpha_res, alpha_post,
                                    s_pre, s_res, s_post, gates);
  k_inner_in<<<4096, 256, 0, stream>>>(x, gates, inner_in);
  k_gemm<<<512, 256, 0, stream>>>(inner_in, w_inner_bf, inner_out);
  k_out<<<4096, 256, 0, stream>>>(x, gates, inner_out, out);
}

// Round 3
// 172.809 us; speedup vs baseline: 1.8669x; 1.4103x over previous
//
#include <hip/hip_runtime.h>
#include <hip/hip_bf16.h>

// Problem constants (B=2, T=2048, H=4, D=2048)
#define FD 8192      // H*D flat dim
#define DD 2048      // D
#define NH 4         // heads
#define NT 4096      // B*T tokens
#define NG 24        // gate rows: 4 pre + 16 res + 4 post
#define NGP 32       // padded gate rows for MFMA
#define KSPLIT 32
#define KC (FD / KSPLIT)   // 256 k per gates-block
#define CH 64              // k per staging chunk

typedef __attribute__((ext_vector_type(4))) float f32x4;
typedef __attribute__((ext_vector_type(8))) short short8;

__device__ inline unsigned short f2bf(float f) {
  __hip_bfloat16 h = __float2bfloat16(f);
  unsigned short u; __builtin_memcpy(&u, &h, 2); return u;
}
__device__ inline float bf2f(unsigned short u) {
  __hip_bfloat16 h; __builtin_memcpy(&h, &u, 2); return __bfloat162float(h);
}

// ---------------------------------------------------------------- prep
__global__ __launch_bounds__(256) void k_prep(
    const float* __restrict__ w_inner,
    const float* __restrict__ w_pre,
    const float* __restrict__ w_res,
    const float* __restrict__ w_post,
    const float* __restrict__ norm_w,
    unsigned short* __restrict__ w_inner_bf,
    unsigned short* __restrict__ wnb)
{
  int stride = gridDim.x * blockDim.x;
  int gid = blockIdx.x * blockDim.x + threadIdx.x;
  for (int i = gid; i < DD * DD; i += stride) w_inner_bf[i] = f2bf(w_inner[i]);
  for (int i = gid; i < NGP * FD; i += stride) {
    int j = i >> 13, k = i & (FD - 1);
    float w = (j < 4) ? w_pre[j * FD + k]
            : (j < 20) ? w_res[(j - 4) * FD + k]
            : (j < 24) ? w_post[(j - 20) * FD + k]
            : 0.0f;
    wnb[i] = f2bf(w * norm_w[k]);
  }
}

// ---------------------------------------------------------------- gates GEMM + sumsq (MFMA)
__global__ __launch_bounds__(256) void k_gates(
    const float* __restrict__ x, const unsigned short* __restrict__ wnb,
    float* __restrict__ partial /* [KSPLIT][NT][NG+1] */)
{
  __shared__ unsigned short xs[128][72];
  const int tb = blockIdx.x;
  const int ks = blockIdx.y;
  const int tid = threadIdx.x;
  const int wave = tid >> 6, lane = tid & 63;
  const int lr = lane & 15, kg = lane >> 4;
  const int t0 = tb * 128;
  const int k0 = ks * KC;
  const int sr = tid >> 4;
  const int sc = (tid & 15) * 4;

  float ssq[8];
#pragma unroll
  for (int i = 0; i < 8; ++i) ssq[i] = 0.f;
  f32x4 acc[2][2] = {};

  for (int ch = 0; ch < KC; ch += CH) {
    __syncthreads();
#pragma unroll
    for (int it = 0; it < 8; ++it) {
      int r = it * 16 + sr;
      f32x4 v = *(const f32x4*)&x[(size_t)(t0 + r) * FD + k0 + ch + sc];
      ssq[it] += v.x * v.x + v.y * v.y + v.z * v.z + v.w * v.w;
      ushort4 o;
      o.x = f2bf(v.x); o.y = f2bf(v.y); o.z = f2bf(v.z); o.w = f2bf(v.w);
      *(ushort4*)&xs[r][sc] = o;
    }
    __syncthreads();
#pragma unroll
    for (int kk = 0; kk < CH; kk += 32) {
      short8 a[2], b[2];
#pragma unroll
      for (int m = 0; m < 2; ++m)
        a[m] = *(const short8*)&xs[wave * 32 + m * 16 + lr][kk + kg * 8];
#pragma unroll
      for (int n = 0; n < 2; ++n)
        b[n] = *(const short8*)&wnb[(size_t)(n * 16 + lr) * FD + k0 + ch + kk + kg * 8];
#pragma unroll
      for (int m = 0; m < 2; ++m)
#pragma unroll
        for (int n = 0; n < 2; ++n)
          acc[m][n] = __builtin_amdgcn_mfma_f32_16x16x32_bf16(a[m], b[n], acc[m][n], 0, 0, 0);
    }
  }

  float* base = &partial[(size_t)ks * NT * (NG + 1)];
#pragma unroll
  for (int m = 0; m < 2; ++m)
#pragma unroll
    for (int n = 0; n < 2; ++n) {
      int g = n * 16 + lr;
      if (g < NG) {
#pragma unroll
        for (int r = 0; r < 4; ++r) {
          int row = wave * 32 + m * 16 + kg * 4 + r;
          base[(size_t)(t0 + row) * (NG + 1) + g] = acc[m][n][r];
        }
      }
    }
#pragma unroll
  for (int it = 0; it < 8; ++it) {
    float v = ssq[it];
    v += __shfl_xor(v, 1);
    v += __shfl_xor(v, 2);
    v += __shfl_xor(v, 4);
    v += __shfl_xor(v, 8);
    if ((tid & 15) == 0) {
      int row = it * 16 + sr;
      base[(size_t)(t0 + row) * (NG + 1) + NG] = v;
    }
  }
}

// ---------------------------------------------------------------- per-token scalars
__global__ __launch_bounds__(256) void k_scalars(
    const float* __restrict__ partial,
    const float* __restrict__ alpha_pre, const float* __restrict__ alpha_res,
    const float* __restrict__ alpha_post,
    const float* __restrict__ s_pre, const float* __restrict__ s_res,
    const float* __restrict__ s_post,
    float* __restrict__ gates /* [NT][24]: a0..3, c0..3, b0..15 */)
{
  int t = blockIdx.x * blockDim.x + threadIdx.x;
  if (t >= NT) return;
  float acc[NG + 1];
#pragma unroll
  for (int j = 0; j <= NG; ++j) acc[j] = 0.f;
  for (int s = 0; s < KSPLIT; ++s) {
    const float* p = &partial[((size_t)s * NT + t) * (NG + 1)];
#pragma unroll
    for (int j = 0; j <= NG; ++j) acc[j] += p[j];
  }
  float rinv = rsqrtf(acc[NG] * (1.0f / FD) + 1e-6f);
  float ap = alpha_pre[0], ar = alpha_res[0], apo = alpha_post[0];

  float out[NG];
#pragma unroll
  for (int h = 0; h < 4; ++h)
    out[h] = 1.f / (1.f + expf(-(ap * rinv * acc[h] + s_pre[h])));
#pragma unroll
  for (int h = 0; h < 4; ++h)
    out[4 + h] = 2.f / (1.f + expf(-(apo * rinv * acc[20 + h] + s_post[h])));

  float m[16]; float mx = -1e30f;
#pragma unroll
  for (int j = 0; j < 16; ++j) {
    float br = ar * rinv * acc[4 + j] + s_res[j];
    m[j] = br; mx = fmaxf(mx, br);
  }
#pragma unroll
  for (int j = 0; j < 16; ++j) m[j] = expf(m[j] - mx);
#pragma unroll
  for (int it = 0; it < 5; ++it) {
#pragma unroll
    for (int h = 0; h < 4; ++h) {
      float rs = m[h*4] + m[h*4+1] + m[h*4+2] + m[h*4+3];
      float inv = 1.f / (rs + 1e-12f);
      m[h*4] *= inv; m[h*4+1] *= inv; m[h*4+2] *= inv; m[h*4+3] *= inv;
    }
#pragma unroll
    for (int k = 0; k < 4; ++k) {
      float cs = m[k] + m[4+k] + m[8+k] + m[12+k];
      float inv = 1.f / (cs + 1e-12f);
      m[k] *= inv; m[4+k] *= inv; m[8+k] *= inv; m[12+k] *= inv;
    }
  }
#pragma unroll
  for (int j = 0; j < 16; ++j) out[8 + j] = m[j];

  float* gt = &gates[(size_t)t * 24];
#pragma unroll
  for (int j = 0; j < NG; ++j) gt[j] = out[j];
}

// ---------------------------------------------------------------- inner_in = sum_h a_h * x_h  (bf16 out)
__global__ __launch_bounds__(256) void k_inner_in(
    const float* __restrict__ x, const float* __restrict__ gates,
    unsigned short* __restrict__ inner_in)
{
  int t = blockIdx.x, tid = threadIdx.x;
  const float* g = &gates[(size_t)t * 24];
  float a0 = g[0], a1 = g[1], a2 = g[2], a3 = g[3];
  const float* xt = &x[(size_t)t * FD];
#pragma unroll
  for (int it = 0; it < 2; ++it) {
    int d = (it * 256 + tid) * 4;
    f32x4 v0 = *(const f32x4*)&xt[0 * DD + d];
    f32x4 v1 = *(const f32x4*)&xt[1 * DD + d];
    f32x4 v2 = *(const f32x4*)&xt[2 * DD + d];
    f32x4 v3 = *(const f32x4*)&xt[3 * DD + d];
    f32x4 s = a0 * v0 + a1 * v1 + a2 * v2 + a3 * v3;
    ushort4 o;
    o.x = f2bf(s.x); o.y = f2bf(s.y); o.z = f2bf(s.z); o.w = f2bf(s.w);
    *(ushort4*)&inner_in[(size_t)t * DD + d] = o;
  }
}

// ---------------------------------------------------------------- GEMM: inner_out = inner_in @ w_inner^T
// m97 structure: 128x128 tile, BK=64, global_load_lds staging, 4 waves x (4x4) frags.
__global__ __launch_bounds__(256) void k_gemm(
    const unsigned short* __restrict__ A,   // inner_in [4096][2048]
    const unsigned short* __restrict__ B,   // w_inner_bf [2048][2048]
    unsigned short* __restrict__ C)         // inner_out [4096][2048]
{
  __shared__ unsigned short As[128 * 64];
  __shared__ unsigned short Bs[128 * 64];
  const int bid = blockIdx.x;
  const int bm = bid >> 4, bn = bid & 15;   // 32 x 16 tiles of 128x128
  const int tid = threadIdx.x;
  const int wave = tid >> 6, lane = tid & 63;
  const int wm = wave >> 1, wn_ = wave & 1; // 2x2 waves of 64x64
  const int lr = lane & 15, kg = lane >> 4;

  // staging geometry: chunk c = it*256 + tid covers LDS bytes [c*16, c*16+16)
  // = tile row c/8, col elements (c%8)*8 .. +8. Per-wave dest = base + lane*16 (linear).
  const int srow = tid >> 3;          // 0..31, +32 per it
  const int scol = (tid & 7) * 8;     // element col within BK=64
  const unsigned short* a_src = &A[(size_t)(bm * 128 + srow) * 2048 + scol];
  const unsigned short* b_src = &B[(size_t)(bn * 128 + srow) * 2048 + scol];

  f32x4 acc[4][4] = {};

  for (int kt = 0; kt < 2048; kt += 64) {
    __syncthreads();
#pragma unroll
    for (int it = 0; it < 4; ++it)
      __builtin_amdgcn_global_load_lds(
          (const __attribute__((address_space(1))) void*)(a_src + (size_t)it * 32 * 2048 + kt),
          (__attribute__((address_space(3))) void*)(&As[it * 2048 + tid * 8]), 16, 0, 0);
#pragma unroll
    for (int it = 0; it < 4; ++it)
      __builtin_amdgcn_global_load_lds(
          (const __attribute__((address_space(1))) void*)(b_src + (size_t)it * 32 * 2048 + kt),
          (__attribute__((address_space(3))) void*)(&Bs[it * 2048 + tid * 8]), 16, 0, 0);
    __syncthreads();
#pragma unroll
    for (int kk = 0; kk < 64; kk += 32) {
      short8 a[4], b[4];
#pragma unroll
      for (int m = 0; m < 4; ++m)
        a[m] = *(const short8*)&As[(wm * 64 + m * 16 + lr) * 64 + kk + kg * 8];
#pragma unroll
      for (int n = 0; n < 4; ++n)
        b[n] = *(const short8*)&Bs[(wn_ * 64 + n * 16 + lr) * 64 + kk + kg * 8];
#pragma unroll
      for (int m = 0; m < 4; ++m)
#pragma unroll
        for (int n = 0; n < 4; ++n)
          acc[m][n] = __builtin_amdgcn_mfma_f32_16x16x32_bf16(a[m], b[n], acc[m][n], 0, 0, 0);
    }
  }

  const int row_base = bm * 128 + wm * 64;
  const int col_base = bn * 128 + wn_ * 64;
#pragma unroll
  for (int m = 0; m < 4; ++m)
#pragma unroll
    for (int n = 0; n < 4; ++n) {
      int col = col_base + n * 16 + lr;
#pragma unroll
      for (int r = 0; r < 4; ++r) {
        int row = row_base + m * 16 + kg * 4 + r;
        C[(size_t)row * 2048 + col] = f2bf(acc[m][n][r]);
      }
    }
}

// ---------------------------------------------------------------- out = carry + write
__global__ __launch_bounds__(256) void k_out(
    const float* __restrict__ x, const float* __restrict__ gates,
    const unsigned short* __restrict__ inner_out, float* __restrict__ out)
{
  int t = blockIdx.x, tid = threadIdx.x;
  const float* g = &gates[(size_t)t * 24];
  float c[4], bl[16];
#pragma unroll
  for (int h = 0; h < 4; ++h) c[h] = g[4 + h];
#pragma unroll
  for (int j = 0; j < 16; ++j) bl[j] = g[8 + j];
  const float* xt = &x[(size_t)t * FD];
  float* ot = &out[(size_t)t * FD];
  const unsigned short* iot = &inner_out[(size_t)t * DD];
#pragma unroll
  for (int it = 0; it < 2; ++it) {
    int d = (it * 256 + tid) * 4;
    f32x4 xk[4];
#pragma unroll
    for (int k = 0; k < 4; ++k) xk[k] = *(const f32x4*)&xt[k * DD + d];
    ushort4 u = *(const ushort4*)&iot[d];
    f32x4 io; io.x = bf2f(u.x); io.y = bf2f(u.y); io.z = bf2f(u.z); io.w = bf2f(u.w);
#pragma unroll
    for (int h = 0; h < 4; ++h) {
      f32x4 o = c[h] * io
              + bl[h*4+0] * xk[0] + bl[h*4+1] * xk[1]
              + bl[h*4+2] * xk[2] + bl[h*4+3] * xk[3];
      *(f32x4*)&ot[h * DD + d] = o;
    }
  }
}

// ---------------------------------------------------------------- launch
extern "C" void kernel_launch(void* const* d_in, const int* in_sizes, int n_in,
                              void* d_out, int out_size, void* d_ws, size_t ws_size,
                              hipStream_t stream) {
  const float* x          = (const float*)d_in[0];
  const float* norm_w     = (const float*)d_in[1];
  const float* w_pre      = (const float*)d_in[2];
  const float* w_res      = (const float*)d_in[3];
  const float* w_post     = (const float*)d_in[4];
  const float* alpha_pre  = (const float*)d_in[5];
  const float* alpha_res  = (const float*)d_in[6];
  const float* alpha_post = (const float*)d_in[7];
  const float* s_pre      = (const float*)d_in[8];
  const float* s_res      = (const float*)d_in[9];
  const float* s_post     = (const float*)d_in[10];
  const float* w_inner    = (const float*)d_in[11];
  float* out = (float*)d_out;

  char* ws = (char*)d_ws;
  size_t off = 0;
  auto alloc = [&](size_t bytes) -> void* {
    void* p = ws + off;
    off = (off + bytes + 255) & ~(size_t)255;
    return p;
  };
  unsigned short* w_inner_bf = (unsigned short*)alloc((size_t)DD * DD * 2);        // 8.4 MB
  unsigned short* inner_in   = (unsigned short*)alloc((size_t)NT * DD * 2);        // 16.8 MB
  unsigned short* inner_out  = (unsigned short*)alloc((size_t)NT * DD * 2);        // 16.8 MB
  unsigned short* wnb        = (unsigned short*)alloc((size_t)NGP * FD * 2);       // 0.52 MB
  float* partial = (float*)alloc((size_t)KSPLIT * NT * (NG + 1) * 4);              // 13.1 MB
  float* gates   = (float*)alloc((size_t)NT * 24 * 4);                             // 0.39 MB

  k_prep<<<1024, 256, 0, stream>>>(w_inner, w_pre, w_res, w_post, norm_w, w_inner_bf, wnb);
  k_gates<<<dim3(32, 32), 256, 0, stream>>>(x, wnb, partial);
  k_scalars<<<16, 256, 0, stream>>>(partial, alpha_pre, alpha_res, alpha_post,
                                    s_pre, s_res, s_post, gates);
  k_inner_in<<<4096, 256, 0, stream>>>(x, gates, inner_in);
  k_gemm<<<512, 256, 0, stream>>>(inner_in, w_inner_bf, inner_out);
  k_out<<<4096, 256, 0, stream>>>(x, gates, inner_out, out);
}